// Round 1
// baseline (558.384 us; speedup 1.0000x reference)
//
#include <hip/hip_runtime.h>
#include <hip/hip_bf16.h>

// Problem constants
#define MROWS 4096
#define TSTEPS 100
#define EMB 64
#define HID 128
#define GATES 512        // 4*HID
#define KTOT 192         // EMB + HID
#define ROWS_PB 32       // rows per block (one direction)
#define SROW 200         // padded A-panel row stride in f16 elems (400B, 16B aligned)

typedef _Float16 half8 __attribute__((ext_vector_type(8)));
typedef float f32x4 __attribute__((ext_vector_type(4)));

__device__ __forceinline__ float sigm_f(float x) {
    return __fdividef(1.f, 1.f + __expf(-x));
}
__device__ __forceinline__ float tanh_f(float x) {
    // 1 - 2/(e^{2x}+1); robust at +-inf
    return 1.f - __fdividef(2.f, __expf(2.f * x) + 1.f);
}

// ---------------------------------------------------------------------------
// Kernel 1: scores = softmax(relu(obs @ attn_W + attn_b), axis=1)  (256 x 100)
// ---------------------------------------------------------------------------
__global__ void attn_scores_kernel(const float* __restrict__ obs,
                                   const float* __restrict__ attn_W,
                                   const float* __restrict__ attn_b,
                                   float* __restrict__ scores) {
    const int row = blockIdx.x;      // 256 rows
    const int tid = threadIdx.x;     // 128 threads
    __shared__ float obs_s[128];
    __shared__ float red[128];

    obs_s[tid] = obs[row * 128 + tid];
    __syncthreads();

    float s = -1e30f;
    if (tid < 100) {
        float a = attn_b[tid];
        #pragma unroll 4
        for (int k = 0; k < 128; k++) a += obs_s[k] * attn_W[k * 100 + tid];
        s = fmaxf(a, 0.f);
    }
    red[tid] = s;
    __syncthreads();
    for (int off = 64; off > 0; off >>= 1) {
        if (tid < off) red[tid] = fmaxf(red[tid], red[tid + off]);
        __syncthreads();
    }
    const float m = red[0];
    __syncthreads();
    const float e = (tid < 100) ? __expf(s - m) : 0.f;
    red[tid] = e;
    __syncthreads();
    for (int off = 64; off > 0; off >>= 1) {
        if (tid < off) red[tid] += red[tid + off];
        __syncthreads();
    }
    const float inv = __fdividef(1.f, red[0]);
    if (tid < 100) scores[row * 100 + tid] = e * inv;
}

// ---------------------------------------------------------------------------
// Kernel 2: persistent bidirectional LSTM with fused embedding + online pooling
// grid = 256 blocks (128 fwd + 128 bwd), 512 threads (8 waves)
// Each wave owns 16 hidden units; weights live in VGPRs in B-fragment layout.
// ---------------------------------------------------------------------------
__launch_bounds__(512, 2)
__global__ void lstm_kernel(const float* __restrict__ lane_features,
                            const float* __restrict__ embed_W,
                            const float* __restrict__ embed_b,
                            const float* __restrict__ Wih_f,
                            const float* __restrict__ Whh_f,
                            const float* __restrict__ b_f,
                            const float* __restrict__ Wih_b,
                            const float* __restrict__ Whh_b,
                            const float* __restrict__ b_b,
                            const float* __restrict__ h0,
                            const float* __restrict__ c0,
                            const int*   __restrict__ mask,
                            const float* __restrict__ scores,
                            float* __restrict__ out_feat) {
    const int blk = blockIdx.x;
    const int d = blk >> 7;                     // 0 = fwd, 1 = bwd
    const int rowbase = (blk & 127) * ROWS_PB;
    const int tid = threadIdx.x;
    const int wave = tid >> 6;
    const int lane = tid & 63;
    const int lane16 = lane & 15;
    const int quad = lane >> 4;

    const float* Wih = d ? Wih_b : Wih_f;
    const float* Whh = d ? Whh_b : Whh_f;
    const float* bia = d ? b_b : b_f;

    __shared__ __attribute__((aligned(16))) _Float16 panel[2][ROWS_PB][SROW];
    __shared__ float ew_s[4][EMB];
    __shared__ float eb_s[EMB];

    // Stage embedding weights
    if (tid < 256) ew_s[tid >> 6][tid & 63] = embed_W[tid];
    if (tid < 64) eb_s[tid] = embed_b[tid];

    // ---- Preload B fragments into registers (MFMA B layout) ----
    // wave owns units [wave*16, wave*16+16); gate ct's columns = ct*128 + unit
    const int unitg = wave * 16 + lane16;
    half8 Bf[24];   // [ct][ki] -> 24 frags * 8 f16 = 96 VGPRs
    #pragma unroll
    for (int ct = 0; ct < 4; ct++) {
        const int col = ct * 128 + unitg;
        #pragma unroll
        for (int ki = 0; ki < 6; ki++) {
            half8 b;
            #pragma unroll
            for (int j = 0; j < 8; j++) {
                const int kk = ki * 32 + quad * 8 + j;
                const float w = (kk < EMB) ? Wih[kk * GATES + col]
                                           : Whh[(kk - EMB) * GATES + col];
                b[j] = (_Float16)w;
            }
            Bf[ct * 6 + ki] = b;
        }
    }
    float bgate[4];
    #pragma unroll
    for (int ct = 0; ct < 4; ct++) bgate[ct] = bia[ct * 128 + unitg];

    // ---- Per-lane state: 8 (row,unit) pairs in C-layout ----
    float cst[8], fr[8], bk[8], mx[8], as[8];
    const float cinit = c0[d * 128 + unitg];
    #pragma unroll
    for (int p = 0; p < 8; p++) {
        cst[p] = cinit; fr[p] = 0.f; bk[p] = 0.f; mx[p] = -1e30f; as[p] = 0.f;
    }
    int mofs[8];
    #pragma unroll
    for (int p = 0; p < 8; p++) {
        const int row_local = (p >> 2) * 16 + quad * 4 + (p & 3);
        mofs[p] = mask[rowbase + row_local] * 100;
    }

    // ---- Init panel[0]: h part ----
    for (int idx = tid; idx < ROWS_PB * HID; idx += 512) {
        const int r = idx >> 7, u = idx & 127;
        panel[0][r][EMB + u] = (_Float16)h0[d * 128 + u];
    }
    __syncthreads();   // ew_s/eb_s ready

    // ---- Init panel[0]: x part for first step ----
    {
        const int t0 = d ? (TSTEPS - 1) : 0;
        const int r = tid >> 4, cc = (tid & 15) * 4;
        const float* fp = lane_features + (long)(rowbase + r) * 600 + 200 + 4 * t0;
        const float f0 = fp[0], f1 = fp[1], f2 = fp[2], f3 = fp[3];
        #pragma unroll
        for (int j = 0; j < 4; j++) {
            float e = eb_s[cc + j] + f0 * ew_s[0][cc + j] + f1 * ew_s[1][cc + j]
                                   + f2 * ew_s[2][cc + j] + f3 * ew_s[3][cc + j];
            panel[0][r][cc + j] = (_Float16)fmaxf(e, 0.f);
        }
    }
    __syncthreads();

    // ================= main recurrence =================
    for (int s = 0; s < TSTEPS; s++) {
        const int p = s & 1;
        const int t = d ? (TSTEPS - 1 - s) : s;

        f32x4 acc[2][4];
        #pragma unroll
        for (int rt = 0; rt < 2; rt++)
            #pragma unroll
            for (int ct = 0; ct < 4; ct++) acc[rt][ct] = (f32x4){0.f, 0.f, 0.f, 0.f};

        #pragma unroll
        for (int ki = 0; ki < 6; ki++) {
            const half8 a0 = *(const half8*)&panel[p][lane16][ki * 32 + quad * 8];
            const half8 a1 = *(const half8*)&panel[p][16 + lane16][ki * 32 + quad * 8];
            #pragma unroll
            for (int ct = 0; ct < 4; ct++) {
                acc[0][ct] = __builtin_amdgcn_mfma_f32_16x16x32_f16(a0, Bf[ct * 6 + ki], acc[0][ct], 0, 0, 0);
                acc[1][ct] = __builtin_amdgcn_mfma_f32_16x16x32_f16(a1, Bf[ct * 6 + ki], acc[1][ct], 0, 0, 0);
            }
        }

        // attention weights for this step (L1-resident table)
        float aw[8];
        #pragma unroll
        for (int pp = 0; pp < 8; pp++) aw[pp] = scores[mofs[pp] + t];

        // ---- cell update + online pooling ----
        #pragma unroll
        for (int rt = 0; rt < 2; rt++) {
            #pragma unroll
            for (int r = 0; r < 4; r++) {
                const int pp = rt * 4 + r;
                const int row_local = rt * 16 + quad * 4 + r;
                const float gi = acc[rt][0][r] + bgate[0];
                const float gf = acc[rt][1][r] + bgate[1];
                const float gg = acc[rt][2][r] + bgate[2];
                const float go = acc[rt][3][r] + bgate[3];
                const float cn = sigm_f(gf) * cst[pp] + sigm_f(gi) * tanh_f(gg);
                const float h = sigm_f(go) * tanh_f(cn);
                cst[pp] = cn;
                if (t == 0) fr[pp] = h;              // front: h after t_orig==0
                if (t == TSTEPS - 1) bk[pp] = h;     // back:  h after t_orig==99
                mx[pp] = fmaxf(mx[pp], h);
                as[pp] += aw[pp] * h;
                panel[1 - p][row_local][EMB + unitg] = (_Float16)h;
            }
        }

        // ---- embed x for next step into the other buffer ----
        if (s < TSTEPS - 1) {
            const int tn = d ? (TSTEPS - 2 - s) : (s + 1);
            const int r = tid >> 4, cc = (tid & 15) * 4;
            const float* fp = lane_features + (long)(rowbase + r) * 600 + 200 + 4 * tn;
            const float f0 = fp[0], f1 = fp[1], f2 = fp[2], f3 = fp[3];
            #pragma unroll
            for (int j = 0; j < 4; j++) {
                float e = eb_s[cc + j] + f0 * ew_s[0][cc + j] + f1 * ew_s[1][cc + j]
                                       + f2 * ew_s[2][cc + j] + f3 * ew_s[3][cc + j];
                panel[1 - p][r][cc + j] = (_Float16)fmaxf(e, 0.f);
            }
        }
        __syncthreads();
    }

    // ---- write pooled features: [front | back | max | attn] each 256 (fwd|bwd 128) ----
    #pragma unroll
    for (int pp = 0; pp < 8; pp++) {
        const int row_local = (pp >> 2) * 16 + quad * 4 + (pp & 3);
        const long ro = (long)(rowbase + row_local) * 1024;
        const int cu = d * 128 + unitg;
        out_feat[ro + cu] = fr[pp];
        out_feat[ro + 256 + cu] = bk[pp];
        out_feat[ro + 512 + cu] = mx[pp];
        out_feat[ro + 768 + cu] = as[pp];
    }
}

// ---------------------------------------------------------------------------
// Kernel 3: out = relu(out_feat(4096x1024) @ enc_W(1024x128) + enc_b)
// 256 blocks x 256 threads; 16 rows per block; fp32 VALU
// ---------------------------------------------------------------------------
__global__ void enc_kernel(const float* __restrict__ out_feat,
                           const float* __restrict__ enc_W,
                           const float* __restrict__ enc_b,
                           float* __restrict__ out) {
    const int rowb = blockIdx.x * 16;
    const int tid = threadIdx.x;
    const int col = tid & 127;
    const int rh = tid >> 7;     // 0/1: which 8-row half
    __shared__ float xs[16][128];

    float acc[8] = {0.f, 0.f, 0.f, 0.f, 0.f, 0.f, 0.f, 0.f};

    for (int kc = 0; kc < 8; kc++) {
        #pragma unroll
        for (int i = 0; i < 8; i++) {
            const int idx = i * 256 + tid;
            const int r = idx >> 7, kk = idx & 127;
            xs[r][kk] = out_feat[(long)(rowb + r) * 1024 + kc * 128 + kk];
        }
        __syncthreads();
        for (int kk = 0; kk < 128; kk++) {
            const float wv = enc_W[(kc * 128 + kk) * 128 + col];
            #pragma unroll
            for (int i = 0; i < 8; i++) acc[i] += xs[rh * 8 + i][kk] * wv;
        }
        __syncthreads();
    }
    const float bb = enc_b[col];
    #pragma unroll
    for (int i = 0; i < 8; i++) {
        out[(long)(rowb + rh * 8 + i) * 128 + col] = fmaxf(acc[i] + bb, 0.f);
    }
}

// ---------------------------------------------------------------------------
extern "C" void kernel_launch(void* const* d_in, const int* in_sizes, int n_in,
                              void* d_out, int out_size, void* d_ws, size_t ws_size,
                              hipStream_t stream) {
    const float* lane_features = (const float*)d_in[0];
    const float* obs_encoding  = (const float*)d_in[1];
    const float* embed_W = (const float*)d_in[2];
    const float* embed_b = (const float*)d_in[3];
    const float* attn_W  = (const float*)d_in[4];
    const float* attn_b  = (const float*)d_in[5];
    const float* Wih_f   = (const float*)d_in[6];
    const float* Whh_f   = (const float*)d_in[7];
    const float* b_f     = (const float*)d_in[8];
    const float* Wih_b   = (const float*)d_in[9];
    const float* Whh_b   = (const float*)d_in[10];
    const float* b_b     = (const float*)d_in[11];
    const float* h0      = (const float*)d_in[12];
    const float* c0      = (const float*)d_in[13];
    const float* enc_W   = (const float*)d_in[14];
    const float* enc_b   = (const float*)d_in[15];
    const int*   mask    = (const int*)d_in[16];

    float* scores   = (float*)d_ws;                          // 256*100 f32
    float* out_feat = (float*)((char*)d_ws + 131072);        // 4096*1024 f32 (16 MB)
    float* out      = (float*)d_out;                         // 4096*128 f32

    attn_scores_kernel<<<256, 128, 0, stream>>>(obs_encoding, attn_W, attn_b, scores);
    lstm_kernel<<<256, 512, 0, stream>>>(lane_features, embed_W, embed_b,
                                         Wih_f, Whh_f, b_f, Wih_b, Whh_b, b_b,
                                         h0, c0, mask, scores, out_feat);
    enc_kernel<<<256, 256, 0, stream>>>(out_feat, enc_W, enc_b, out);
}

// Round 5
// 462.101 us; speedup vs baseline: 1.2084x; 1.2084x over previous
//
#include <hip/hip_runtime.h>
#include <hip/hip_bf16.h>

// Problem constants
#define MROWS 4096
#define TSTEPS 100
#define EMB 64
#define HID 128
#define GATES 512        // 4*HID
#define KTOT 192         // EMB + HID
#define ROWS_PB 32       // rows per block (one direction)
#define SROW 200         // padded A-panel row stride in f16 elems (400B, 16B aligned)

typedef _Float16 half8 __attribute__((ext_vector_type(8)));
typedef _Float16 half4v __attribute__((ext_vector_type(4)));
typedef float f32x4 __attribute__((ext_vector_type(4)));

__device__ __forceinline__ float sigm_f(float x) {
    return __fdividef(1.f, 1.f + __expf(-x));
}
__device__ __forceinline__ float tanh_f(float x) {
    // 1 - 2/(e^{2x}+1); robust at +-inf
    return 1.f - __fdividef(2.f, __expf(2.f * x) + 1.f);
}

// ---------------------------------------------------------------------------
// Kernel 1: scores = softmax(relu(obs @ attn_W + attn_b), axis=1)  (256 x 100)
// EXACT round-1 code (proven).
// ---------------------------------------------------------------------------
__global__ void attn_scores_kernel(const float* __restrict__ obs,
                                   const float* __restrict__ attn_W,
                                   const float* __restrict__ attn_b,
                                   float* __restrict__ scores) {
    const int row = blockIdx.x;      // 256 rows
    const int tid = threadIdx.x;     // 128 threads
    __shared__ float obs_s[128];
    __shared__ float red[128];

    obs_s[tid] = obs[row * 128 + tid];
    __syncthreads();

    float s = -1e30f;
    if (tid < 100) {
        float a = attn_b[tid];
        #pragma unroll 4
        for (int k = 0; k < 128; k++) a += obs_s[k] * attn_W[k * 100 + tid];
        s = fmaxf(a, 0.f);
    }
    red[tid] = s;
    __syncthreads();
    for (int off = 64; off > 0; off >>= 1) {
        if (tid < off) red[tid] = fmaxf(red[tid], red[tid + off]);
        __syncthreads();
    }
    const float m = red[0];
    __syncthreads();
    const float e = (tid < 100) ? __expf(s - m) : 0.f;
    red[tid] = e;
    __syncthreads();
    for (int off = 64; off > 0; off >>= 1) {
        if (tid < off) red[tid] += red[tid + off];
        __syncthreads();
    }
    const float inv = __fdividef(1.f, red[0]);
    if (tid < 100) scores[row * 100 + tid] = e * inv;
}

// ---------------------------------------------------------------------------
// Kernel 1b: encWT[c][k] = (f16) enc_W[k][c]   (1024x128 -> 128x1024 f16)
// ---------------------------------------------------------------------------
__global__ void encw_prep_kernel(const float* __restrict__ enc_W,
                                 _Float16* __restrict__ encWT) {
    __shared__ float tile[64][129];
    const int k0 = blockIdx.x * 64;
    const int tid = threadIdx.x;     // 256
    #pragma unroll
    for (int i = 0; i < 32; i++) {
        const int idx = tid + i * 256;
        const int rr = idx >> 7, cc = idx & 127;
        tile[rr][cc] = enc_W[(k0 + rr) * 128 + cc];
    }
    __syncthreads();
    const int c = tid >> 1, hh = tid & 1;
    #pragma unroll
    for (int j = 0; j < 32; j++) {
        encWT[c * 1024 + k0 + hh * 32 + j] = (_Float16)tile[hh * 32 + j][c];
    }
}

// ---------------------------------------------------------------------------
// Kernel 2: persistent bidirectional LSTM, fused embedding + online pooling.
// Round-1 numerics (proven); structural wins: att_s LDS gather, register
// embed weights, feature prefetch. out_feat stays f32 (round-1 write path).
// ---------------------------------------------------------------------------
__launch_bounds__(512, 2)
__global__ void lstm_kernel(const float* __restrict__ lane_features,
                            const float* __restrict__ embed_W,
                            const float* __restrict__ embed_b,
                            const float* __restrict__ Wih_f,
                            const float* __restrict__ Whh_f,
                            const float* __restrict__ b_f,
                            const float* __restrict__ Wih_b,
                            const float* __restrict__ Whh_b,
                            const float* __restrict__ b_b,
                            const float* __restrict__ h0,
                            const float* __restrict__ c0,
                            const int*   __restrict__ mask,
                            const float* __restrict__ scores,
                            float* __restrict__ out_feat) {
    const int blk = blockIdx.x;
    const int d = blk >> 7;                     // 0 = fwd, 1 = bwd
    const int rowbase = (blk & 127) * ROWS_PB;
    const int tid = threadIdx.x;
    const int wave = tid >> 6;
    const int lane = tid & 63;
    const int lane16 = lane & 15;
    const int quad = lane >> 4;

    const float* Wih = d ? Wih_b : Wih_f;
    const float* Whh = d ? Whh_b : Whh_f;
    const float* bia = d ? b_b : b_f;

    __shared__ __attribute__((aligned(16))) _Float16 panel[2][ROWS_PB][SROW];
    __shared__ float att_s[ROWS_PB][100];

    // ---- Per-thread embed weights (columns cc..cc+3) ----
    const int erow = tid >> 4;                  // row this thread embeds
    const int cc = (tid & 15) * 4;
    float ew_r[4][4], eb_r[4];
    #pragma unroll
    for (int j = 0; j < 4; j++) {
        #pragma unroll
        for (int jj = 0; jj < 4; jj++) ew_r[j][jj] = embed_W[j * EMB + cc + jj];
    }
    #pragma unroll
    for (int jj = 0; jj < 4; jj++) eb_r[jj] = embed_b[cc + jj];

    // ---- att gather: att_s[r][t] = scores[mask[r]*100 + t] (one time) ----
    {
        const int r = tid >> 4, tcol = tid & 15;
        const int mr = mask[rowbase + r];
        for (int t = tcol; t < 100; t += 16) att_s[r][t] = scores[mr * 100 + t];
    }

    // ---- Preload B fragments (MFMA B layout), unscaled (round-1) ----
    const int unitg = wave * 16 + lane16;
    half8 Bf[24];   // [ct][ki]
    #pragma unroll
    for (int ct = 0; ct < 4; ct++) {
        const int col = ct * 128 + unitg;
        #pragma unroll
        for (int ki = 0; ki < 6; ki++) {
            half8 b;
            #pragma unroll
            for (int j = 0; j < 8; j++) {
                const int kk = ki * 32 + quad * 8 + j;
                const float w = (kk < EMB) ? Wih[kk * GATES + col]
                                           : Whh[(kk - EMB) * GATES + col];
                b[j] = (_Float16)w;
            }
            Bf[ct * 6 + ki] = b;
        }
    }
    float bgate[4];
    #pragma unroll
    for (int ct = 0; ct < 4; ct++) bgate[ct] = bia[ct * 128 + unitg];

    // ---- Per-lane state: 8 (row,unit) pairs in C-layout ----
    float cst[8], mx[8], as[8], h0s[8], hl[8];
    const float cinit = c0[d * 128 + unitg];
    #pragma unroll
    for (int p = 0; p < 8; p++) {
        cst[p] = cinit; mx[p] = -1e30f; as[p] = 0.f; h0s[p] = 0.f; hl[p] = 0.f;
    }

    // ---- Init panel[0]: h part ----
    for (int idx = tid; idx < ROWS_PB * HID; idx += 512) {
        const int r = idx >> 7, u = idx & 127;
        panel[0][r][EMB + u] = (_Float16)h0[d * 128 + u];
    }

    // ---- Init panel[0]: x for first step ----
    {
        const int t0 = d ? (TSTEPS - 1) : 0;
        const float4 fv = *(const float4*)(lane_features + (long)(rowbase + erow) * 600 + 200 + 4 * t0);
        #pragma unroll
        for (int jj = 0; jj < 4; jj++) {
            float e = eb_r[jj] + fv.x * ew_r[0][jj] + fv.y * ew_r[1][jj]
                               + fv.z * ew_r[2][jj] + fv.w * ew_r[3][jj];
            panel[0][erow][cc + jj] = (_Float16)fmaxf(e, 0.f);
        }
    }
    __syncthreads();

    // ================= main recurrence =================
    for (int s = 0; s < TSTEPS; s++) {
        const int p = s & 1;
        const int t = d ? (TSTEPS - 1 - s) : s;

        // prefetch next x features (VMEM latency overlaps MFMA below)
        float4 fv;
        if (s < TSTEPS - 1) {
            const int tn = d ? (TSTEPS - 2 - s) : (s + 1);
            fv = *(const float4*)(lane_features + (long)(rowbase + erow) * 600 + 200 + 4 * tn);
        }

        // attention weights (LDS broadcast reads)
        float aw[8];
        #pragma unroll
        for (int pp = 0; pp < 8; pp++) {
            const int row_local = (pp >> 2) * 16 + quad * 4 + (pp & 3);
            aw[pp] = att_s[row_local][t];
        }

        f32x4 acc[2][4];
        #pragma unroll
        for (int rt = 0; rt < 2; rt++)
            #pragma unroll
            for (int ct = 0; ct < 4; ct++) acc[rt][ct] = (f32x4){0.f, 0.f, 0.f, 0.f};

        #pragma unroll
        for (int ki = 0; ki < 6; ki++) {
            const half8 a0 = *(const half8*)&panel[p][lane16][ki * 32 + quad * 8];
            const half8 a1 = *(const half8*)&panel[p][16 + lane16][ki * 32 + quad * 8];
            #pragma unroll
            for (int ct = 0; ct < 4; ct++) {
                acc[0][ct] = __builtin_amdgcn_mfma_f32_16x16x32_f16(a0, Bf[ct * 6 + ki], acc[0][ct], 0, 0, 0);
                acc[1][ct] = __builtin_amdgcn_mfma_f32_16x16x32_f16(a1, Bf[ct * 6 + ki], acc[1][ct], 0, 0, 0);
            }
        }

        // ---- cell update + online pooling (round-1 math) ----
        #pragma unroll
        for (int rt = 0; rt < 2; rt++) {
            #pragma unroll
            for (int r = 0; r < 4; r++) {
                const int pp = rt * 4 + r;
                const int row_local = rt * 16 + quad * 4 + r;
                const float gi = acc[rt][0][r] + bgate[0];
                const float gf = acc[rt][1][r] + bgate[1];
                const float gg = acc[rt][2][r] + bgate[2];
                const float go = acc[rt][3][r] + bgate[3];
                const float cn = sigm_f(gf) * cst[pp] + sigm_f(gi) * tanh_f(gg);
                const float h = sigm_f(go) * tanh_f(cn);
                cst[pp] = cn;
                hl[pp] = h;
                mx[pp] = fmaxf(mx[pp], h);
                as[pp] = fmaf(aw[pp], h, as[pp]);
                panel[1 - p][row_local][EMB + unitg] = (_Float16)h;
            }
        }
        if (s == 0) {
            #pragma unroll
            for (int pp = 0; pp < 8; pp++) h0s[pp] = hl[pp];
        }

        // ---- embed prefetched x into the other buffer ----
        if (s < TSTEPS - 1) {
            float e0 = eb_r[0] + fv.x * ew_r[0][0] + fv.y * ew_r[1][0] + fv.z * ew_r[2][0] + fv.w * ew_r[3][0];
            float e1 = eb_r[1] + fv.x * ew_r[0][1] + fv.y * ew_r[1][1] + fv.z * ew_r[2][1] + fv.w * ew_r[3][1];
            float e2 = eb_r[2] + fv.x * ew_r[0][2] + fv.y * ew_r[1][2] + fv.z * ew_r[2][2] + fv.w * ew_r[3][2];
            float e3 = eb_r[3] + fv.x * ew_r[0][3] + fv.y * ew_r[1][3] + fv.z * ew_r[2][3] + fv.w * ew_r[3][3];
            panel[1 - p][erow][cc]     = (_Float16)fmaxf(e0, 0.f);
            panel[1 - p][erow][cc + 1] = (_Float16)fmaxf(e1, 0.f);
            panel[1 - p][erow][cc + 2] = (_Float16)fmaxf(e2, 0.f);
            panel[1 - p][erow][cc + 3] = (_Float16)fmaxf(e3, 0.f);
        }
        __syncthreads();
    }

    // ---- pooled features: [front | back | max | attn], f32 (round-1 path) ----
    #pragma unroll
    for (int pp = 0; pp < 8; pp++) {
        const int row_local = (pp >> 2) * 16 + quad * 4 + (pp & 3);
        const long ro = (long)(rowbase + row_local) * 1024;
        const int cu = d * 128 + unitg;
        const float fr = d ? hl[pp] : h0s[pp];
        const float bk = d ? h0s[pp] : hl[pp];
        out_feat[ro + cu]       = fr;
        out_feat[ro + 256 + cu] = bk;
        out_feat[ro + 512 + cu] = mx[pp];
        out_feat[ro + 768 + cu] = as[pp];
    }
}

// ---------------------------------------------------------------------------
// Kernel 3: out = relu(out_feat(4096x1024,f32) @ enc_W(1024x128) + enc_b)
// MFMA f16 with in-kernel f32->f16 staging. 256 blocks x 256 thr.
// ---------------------------------------------------------------------------
__launch_bounds__(256, 2)
__global__ void enc_kernel(const float* __restrict__ out_feat,
                           const _Float16* __restrict__ encWT,
                           const float* __restrict__ enc_b,
                           float* __restrict__ out) {
    const int rb = blockIdx.x * 16;
    const int tid = threadIdx.x;
    const int wave = tid >> 6;
    const int lane = tid & 63;
    const int lane16 = lane & 15;
    const int quad = lane >> 4;

    __shared__ __attribute__((aligned(16))) _Float16 A16[16][1032];

    // stage 16 rows x 1024 of A: load f32, convert to f16
    #pragma unroll
    for (int i = 0; i < 16; i++) {
        const int u = tid + i * 256;            // 0..4095, units of float4
        const int row = u >> 8, kc = u & 255;
        const float4 v = *(const float4*)(out_feat + (long)(rb + row) * 1024 + kc * 4);
        half4v hv;
        hv[0] = (_Float16)v.x; hv[1] = (_Float16)v.y;
        hv[2] = (_Float16)v.z; hv[3] = (_Float16)v.w;
        *(half4v*)&A16[row][kc * 4] = hv;
    }
    __syncthreads();

    const int col0 = wave * 32 + lane16;
    f32x4 acc0 = {0.f, 0.f, 0.f, 0.f}, acc1 = {0.f, 0.f, 0.f, 0.f};

    #pragma unroll 4
    for (int it = 0; it < 32; it++) {
        const half8 a  = *(const half8*)&A16[lane16][it * 32 + quad * 8];
        const half8 b0 = *(const half8*)(encWT + (long)col0 * 1024 + it * 32 + quad * 8);
        const half8 b1 = *(const half8*)(encWT + (long)(col0 + 16) * 1024 + it * 32 + quad * 8);
        acc0 = __builtin_amdgcn_mfma_f32_16x16x32_f16(a, b0, acc0, 0, 0, 0);
        acc1 = __builtin_amdgcn_mfma_f32_16x16x32_f16(a, b1, acc1, 0, 0, 0);
    }

    const float bb0 = enc_b[col0], bb1 = enc_b[col0 + 16];
    #pragma unroll
    for (int r = 0; r < 4; r++) {
        const int row = rb + quad * 4 + r;
        out[(long)row * 128 + col0]      = fmaxf(acc0[r] + bb0, 0.f);
        out[(long)row * 128 + col0 + 16] = fmaxf(acc1[r] + bb1, 0.f);
    }
}

// ---------------------------------------------------------------------------
extern "C" void kernel_launch(void* const* d_in, const int* in_sizes, int n_in,
                              void* d_out, int out_size, void* d_ws, size_t ws_size,
                              hipStream_t stream) {
    const float* lane_features = (const float*)d_in[0];
    const float* obs_encoding  = (const float*)d_in[1];
    const float* embed_W = (const float*)d_in[2];
    const float* embed_b = (const float*)d_in[3];
    const float* attn_W  = (const float*)d_in[4];
    const float* attn_b  = (const float*)d_in[5];
    const float* Wih_f   = (const float*)d_in[6];
    const float* Whh_f   = (const float*)d_in[7];
    const float* b_f     = (const float*)d_in[8];
    const float* Wih_b   = (const float*)d_in[9];
    const float* Whh_b   = (const float*)d_in[10];
    const float* b_b     = (const float*)d_in[11];
    const float* h0      = (const float*)d_in[12];
    const float* c0      = (const float*)d_in[13];
    const float* enc_W   = (const float*)d_in[14];
    const float* enc_b   = (const float*)d_in[15];
    const int*   mask    = (const int*)d_in[16];

    float*     scores   = (float*)d_ws;                            // 256*100 f32
    _Float16*  encWT    = (_Float16*)((char*)d_ws + (128 << 10));  // 128*1024 f16 (256 KB)
    float*     out_feat = (float*)((char*)d_ws + (384 << 10));     // 4096*1024 f32 (16 MB)
    float*     out      = (float*)d_out;                           // 4096*128 f32

    attn_scores_kernel<<<256, 128, 0, stream>>>(obs_encoding, attn_W, attn_b, scores);
    encw_prep_kernel<<<16, 256, 0, stream>>>(enc_W, encWT);
    lstm_kernel<<<256, 512, 0, stream>>>(lane_features, embed_W, embed_b,
                                         Wih_f, Whh_f, b_f, Wih_b, Whh_b, b_b,
                                         h0, c0, mask, scores, out_feat);
    enc_kernel<<<256, 256, 0, stream>>>(out_feat, encWT, enc_b, out);
}